// Round 4
// baseline (400.650 us; speedup 1.0000x reference)
//
#include <hip/hip_runtime.h>
#include <hip/hip_bf16.h>
#include <math.h>

// N=50000 nodes, E=600000 edges, H=128.
#define HD 128
#define APAD 136   // LDS row stride in ushorts (+8 pad; 272B rows, 16B aligned)
#define CAP 512    // staged edges per 32-node bucket (mean 384, sd ~20; global fallback)
#define AKW 132    // akey row stride in uints

typedef short bf16x8 __attribute__((ext_vector_type(8)));
typedef float f32x4 __attribute__((ext_vector_type(4)));

static __device__ __forceinline__ unsigned short f2bf(float f) {
  __hip_bfloat16 b = __float2bfloat16(f);
  return *(unsigned short*)&b;
}
static __device__ __forceinline__ float bflo(unsigned int u) {
  return __uint_as_float(u << 16);
}
static __device__ __forceinline__ float bfhi(unsigned int u) {
  return __uint_as_float(u & 0xffff0000u);
}
// monotonic float->uint key: order-preserving for all finite floats
static __device__ __forceinline__ unsigned fkey(float f) {
  unsigned u = __float_as_uint(f);
  return u ^ ((((int)u) >> 31) | 0x80000000u);
}
static __device__ __forceinline__ float funkey(unsigned k) {
  return (k & 0x80000000u) ? __uint_as_float(k ^ 0x80000000u)
                           : __uint_as_float(~k);
}
#define KEY_NEG_INF 0x007FFFFFu  // fkey(-inf)

// ---------------------------------------------------------------------------
// K0: fused weight-fragment pack (blocks 0..39) + bucket histogram (rest).
// Fragment layout: F[((tile*KS+ks)*64+lane)*8+j] =
//   bf16(W[(ks*32+(lane>>4)*8+j)*128 + tile*16+(lane&15)])
// ---------------------------------------------------------------------------
__global__ __launch_bounds__(256) void k_frag_hist(
    const float* __restrict__ enc_w, const float* __restrict__ M_w,
    const float* __restrict__ U_w,
    unsigned short* __restrict__ encf, unsigned short* __restrict__ Pf,
    unsigned short* __restrict__ Qf, unsigned short* __restrict__ Uf,
    const int* __restrict__ ei, int* __restrict__ cnt, int E) {
  const int b = blockIdx.x;
  if (b >= 40) {
    const int e = (b - 40) * 256 + threadIdx.x;
    if (e < E) atomicAdd(&cnt[ei[E + e] >> 5], 1);
    return;
  }
  const float* W; unsigned short* F; int KS; int lb;
  if (b < 8)       { W = enc_w + HD;     F = encf; KS = 4; lb = b; }
  else if (b < 16) { W = M_w;            F = Pf;   KS = 4; lb = b - 8; }
  else if (b < 24) { W = M_w + HD * HD;  F = Qf;   KS = 4; lb = b - 16; }
  else             { W = U_w;            F = Uf;   KS = 8; lb = b - 24; }
  const int gid = lb * 256 + threadIdx.x;
  const int lane = gid & 63;
  const int ks = (gid >> 6) % KS;
  const int tile = gid / (64 * KS);
  const int col = tile * 16 + (lane & 15);
  const int k0 = ks * 32 + (lane >> 4) * 8;
  unsigned short v[8];
#pragma unroll
  for (int j = 0; j < 8; ++j) v[j] = f2bf(W[(size_t)(k0 + j) * HD + col]);
  unsigned short* dst = F + ((size_t)(tile * KS + ks) * 64 + lane) * 8;
#pragma unroll
  for (int j = 0; j < 8; ++j) dst[j] = v[j];
}

// ---------------------------------------------------------------------------
// K1: single-block exclusive scan over nb bucket counts.
// Writes bstart[0..nb] (bstart[nb] = E) and cursor copy.
// ---------------------------------------------------------------------------
__global__ __launch_bounds__(256) void k_scan(
    const int* __restrict__ cnt, int* __restrict__ bstart,
    int* __restrict__ cursor, int nb) {
  __shared__ int s[256];
  const int t = threadIdx.x;
  const int b0 = t * 8;  // 256*8 = 2048 >= nb
  int v[8], sum = 0;
#pragma unroll
  for (int i = 0; i < 8; ++i) {
    v[i] = (b0 + i < nb) ? cnt[b0 + i] : 0;
    sum += v[i];
  }
  s[t] = sum;
  __syncthreads();
  for (int off = 1; off < 256; off <<= 1) {
    int xv = (t >= off) ? s[t - off] : 0;
    __syncthreads();
    if (t >= off) s[t] += xv;
    __syncthreads();
  }
  int run = s[t] - sum;
#pragma unroll
  for (int i = 0; i < 8; ++i) {
    if (b0 + i < nb) {
      bstart[b0 + i] = run;
      cursor[b0 + i] = run;
      run += v[i];
    }
  }
  if (t == 255) bstart[nb] = s[255];
}

// ---------------------------------------------------------------------------
// K2: scatter edges into bucket lists, packing (src | local_row<<16, attr).
// src < 65536 (N=50000), local_row = tgt & 31 (buckets are 32 aligned nodes).
// ---------------------------------------------------------------------------
__global__ __launch_bounds__(256) void k_scatter(
    const int* __restrict__ ei, const float* __restrict__ edge_attr,
    int* __restrict__ cursor, int2* __restrict__ epack, int E) {
  const int e = blockIdx.x * 256 + threadIdx.x;
  if (e >= E) return;
  const int tgt = ei[E + e];
  const int pos = atomicAdd(&cursor[tgt >> 5], 1);
  epack[pos] = make_int2((ei[e] & 0xFFFF) | ((tgt & 31) << 16),
                         __float_as_int(edge_attr[e]));
}

// ---------------------------------------------------------------------------
// K3: MFMA encoder + P/Q (unchanged from round 3).
// ---------------------------------------------------------------------------
__global__ __launch_bounds__(256, 4) void k_enc_pq(
    const float* __restrict__ x, const float* __restrict__ pre_h,
    const float* __restrict__ enc_w, const float* __restrict__ enc_b,
    const float* __restrict__ M_b,
    const unsigned short* __restrict__ encf, const unsigned short* __restrict__ Pf,
    const unsigned short* __restrict__ Qf,
    unsigned short* __restrict__ zg, unsigned short* __restrict__ Pg,
    unsigned short* __restrict__ Qg) {
  __shared__ unsigned short phs[16 * APAD];
  __shared__ unsigned short zsh[16 * APAD];
  __shared__ float xs[16];
  const int t = threadIdx.x;
  const int n0 = blockIdx.x * 16;

  {
    const int r = t >> 4, c0 = (t & 15) * 8;
    const float4 a = *(const float4*)&pre_h[(size_t)(n0 + r) * HD + c0];
    const float4 b = *(const float4*)&pre_h[(size_t)(n0 + r) * HD + c0 + 4];
    unsigned short* d = &phs[r * APAD + c0];
    d[0] = f2bf(a.x); d[1] = f2bf(a.y); d[2] = f2bf(a.z); d[3] = f2bf(a.w);
    d[4] = f2bf(b.x); d[5] = f2bf(b.y); d[6] = f2bf(b.z); d[7] = f2bf(b.w);
  }
  if (t < 16) xs[t] = x[n0 + t];
  __syncthreads();

  const int w = t >> 6, l = t & 63;
  const int m = l & 15, q = l >> 4;

  bf16x8 af[4];
#pragma unroll
  for (int ks = 0; ks < 4; ++ks)
    af[ks] = *(const bf16x8*)&phs[m * APAD + ks * 32 + q * 8];
  f32x4 acc[2] = {{0, 0, 0, 0}, {0, 0, 0, 0}};
#pragma unroll
  for (int tt = 0; tt < 2; ++tt) {
    const int tn = 2 * w + tt;
#pragma unroll
    for (int ks = 0; ks < 4; ++ks) {
      const bf16x8 bf = *(const bf16x8*)&encf[((size_t)(tn * 4 + ks) * 64 + l) * 8];
      acc[tt] = __builtin_amdgcn_mfma_f32_16x16x32_bf16(af[ks], bf, acc[tt], 0, 0, 0);
    }
  }
#pragma unroll
  for (int tt = 0; tt < 2; ++tt) {
    const int col = (2 * w + tt) * 16 + m;
    const float bb = enc_b[col];
    const float w0 = enc_w[col];
#pragma unroll
    for (int r = 0; r < 4; ++r) {
      const int row = q * 4 + r;
      const float zv = fmaxf(acc[tt][r] + bb + xs[row] * w0, 0.0f);
      zsh[row * APAD + col] = f2bf(zv);
    }
  }
  __syncthreads();

  bf16x8 az[4];
#pragma unroll
  for (int ks = 0; ks < 4; ++ks)
    az[ks] = *(const bf16x8*)&zsh[m * APAD + ks * 32 + q * 8];
  {
    const int r = t >> 4, c0 = (t & 15) * 8;
    *(uint4*)&zg[(size_t)(n0 + r) * HD + c0] = *(const uint4*)&zsh[r * APAD + c0];
  }
  __syncthreads();

  f32x4 pacc[2] = {{0, 0, 0, 0}, {0, 0, 0, 0}};
  f32x4 qacc[2] = {{0, 0, 0, 0}, {0, 0, 0, 0}};
#pragma unroll
  for (int tt = 0; tt < 2; ++tt) {
    const int tn = 2 * w + tt;
#pragma unroll
    for (int ks = 0; ks < 4; ++ks) {
      const bf16x8 bp = *(const bf16x8*)&Pf[((size_t)(tn * 4 + ks) * 64 + l) * 8];
      const bf16x8 bq = *(const bf16x8*)&Qf[((size_t)(tn * 4 + ks) * 64 + l) * 8];
      pacc[tt] = __builtin_amdgcn_mfma_f32_16x16x32_bf16(az[ks], bp, pacc[tt], 0, 0, 0);
      qacc[tt] = __builtin_amdgcn_mfma_f32_16x16x32_bf16(az[ks], bq, qacc[tt], 0, 0, 0);
    }
  }
#pragma unroll
  for (int tt = 0; tt < 2; ++tt) {
    const int col = (2 * w + tt) * 16 + m;
    const float mb = M_b[col];
#pragma unroll
    for (int r = 0; r < 4; ++r) {
      const int row = q * 4 + r;
      phs[row * APAD + col] = f2bf(pacc[tt][r] + mb);
      zsh[row * APAD + col] = f2bf(qacc[tt][r]);
    }
  }
  __syncthreads();
  {
    const int r = t >> 4, c0 = (t & 15) * 8;
    *(uint4*)&Pg[(size_t)(n0 + r) * HD + c0] = *(const uint4*)&phs[r * APAD + c0];
    *(uint4*)&Qg[(size_t)(n0 + r) * HD + c0] = *(const uint4*)&zsh[r * APAD + c0];
  }
}

// ---------------------------------------------------------------------------
// K4: edge-parallel gather-max (LDS atomicMax on monotonic keys) + U-GEMM +
// decoder + h column sums.  32 nodes (= 1 bucket)/block, 256 thr = 4 waves.
// ---------------------------------------------------------------------------
__global__ __launch_bounds__(256, 4) void k_gather_update(
    const unsigned short* __restrict__ zg, const unsigned short* __restrict__ Pg,
    const unsigned short* __restrict__ Qg, const float* __restrict__ w_attr,
    const int* __restrict__ bstart, const int2* __restrict__ epack,
    const unsigned short* __restrict__ Uf,
    const float* __restrict__ U_b, const float* __restrict__ dec_w,
    const float* __restrict__ dec_b,
    float* __restrict__ h_out, float* __restrict__ y_out,
    float* __restrict__ hsum, int N) {
  __shared__ unsigned short zsh[32 * APAD];
  // union: akey (32*AKW uints = 16896B)  /  agg bf16 (8704B) + hsh bf16 (8704B)
  __shared__ __align__(16) unsigned aun[4352];
  __shared__ int2 eL[CAP];
  __shared__ float hcol[HD];
  __shared__ float pr[32][8];
  const int t = threadIdx.x;
  const int n0 = blockIdx.x * 32;
  const int bs = bstart[blockIdx.x];
  const int bc = bstart[blockIdx.x + 1] - bs;

  // stage z tile (row-clamped for the 16-node tail bucket)
  {
    const int r = t >> 3, c0 = (t & 7) * 16;
    const int n = min(n0 + r, N - 1);
    *(uint4*)&zsh[r * APAD + c0]     = *(const uint4*)&zg[(size_t)n * HD + c0];
    *(uint4*)&zsh[r * APAD + c0 + 8] = *(const uint4*)&zg[(size_t)n * HD + c0 + 8];
  }
  // init akey to key(-inf): relu(P + -inf) = 0 handles empty nodes for free
  for (int i = t; i < 32 * AKW; i += 256) aun[i] = KEY_NEG_INF;
  for (int i = t; i < min(bc, CAP); i += 256) eL[i] = epack[bs + i];
  if (t < HD) hcol[t] = 0.0f;
  __syncthreads();

  const int w = t >> 6, l = t & 63;
  const float2 wav = ((const float2*)w_attr)[l];

  // ---- edge-parallel gather: wave w takes contiguous chunk of the bucket ----
  {
    const int cs = (bc * w) >> 2;
    const int ce = (bc * (w + 1)) >> 2;
    int i = cs;
    for (; i + 3 < ce; i += 4) {
      const int2 m0 = (i + 0 < CAP) ? eL[i + 0] : epack[bs + i + 0];
      const int2 m1 = (i + 1 < CAP) ? eL[i + 1] : epack[bs + i + 1];
      const int2 m2 = (i + 2 < CAP) ? eL[i + 2] : epack[bs + i + 2];
      const int2 m3 = (i + 3 < CAP) ? eL[i + 3] : epack[bs + i + 3];
      const unsigned q0 = *(const unsigned*)&Qg[(size_t)(m0.x & 0xFFFF) * HD + 2 * l];
      const unsigned q1 = *(const unsigned*)&Qg[(size_t)(m1.x & 0xFFFF) * HD + 2 * l];
      const unsigned q2 = *(const unsigned*)&Qg[(size_t)(m2.x & 0xFFFF) * HD + 2 * l];
      const unsigned q3 = *(const unsigned*)&Qg[(size_t)(m3.x & 0xFFFF) * HD + 2 * l];
      const float a0 = __int_as_float(m0.y), a1 = __int_as_float(m1.y);
      const float a2 = __int_as_float(m2.y), a3 = __int_as_float(m3.y);
      const int r0 = (m0.x >> 16) & 31, r1 = (m1.x >> 16) & 31;
      const int r2 = (m2.x >> 16) & 31, r3 = (m3.x >> 16) & 31;
      atomicMax(&aun[r0 * AKW + 2 * l],     fkey(bflo(q0) + a0 * wav.x));
      atomicMax(&aun[r0 * AKW + 2 * l + 1], fkey(bfhi(q0) + a0 * wav.y));
      atomicMax(&aun[r1 * AKW + 2 * l],     fkey(bflo(q1) + a1 * wav.x));
      atomicMax(&aun[r1 * AKW + 2 * l + 1], fkey(bfhi(q1) + a1 * wav.y));
      atomicMax(&aun[r2 * AKW + 2 * l],     fkey(bflo(q2) + a2 * wav.x));
      atomicMax(&aun[r2 * AKW + 2 * l + 1], fkey(bfhi(q2) + a2 * wav.y));
      atomicMax(&aun[r3 * AKW + 2 * l],     fkey(bflo(q3) + a3 * wav.x));
      atomicMax(&aun[r3 * AKW + 2 * l + 1], fkey(bfhi(q3) + a3 * wav.y));
    }
    for (; i < ce; ++i) {
      const int2 mk = (i < CAP) ? eL[i] : epack[bs + i];
      const unsigned qv = *(const unsigned*)&Qg[(size_t)(mk.x & 0xFFFF) * HD + 2 * l];
      const float a = __int_as_float(mk.y);
      const int rr = (mk.x >> 16) & 31;
      atomicMax(&aun[rr * AKW + 2 * l],     fkey(bflo(qv) + a * wav.x));
      atomicMax(&aun[rr * AKW + 2 * l + 1], fkey(bfhi(qv) + a * wav.y));
    }
  }
  __syncthreads();

  // ---- convert keys -> agg bf16 (in-place into the union head) ----
  unsigned short* agg = (unsigned short*)aun;                // [0, 8704)
  unsigned short* hsh = (unsigned short*)aun + 32 * APAD;    // [8704, 17408)
  {
    const int r = t >> 3, c0 = (t & 7) * 16;
    const int n = min(n0 + r, N - 1);
    unsigned keys[16];
#pragma unroll
    for (int c = 0; c < 16; ++c) keys[c] = aun[r * AKW + c0 + c];
    const uint4 p0 = *(const uint4*)&Pg[(size_t)n * HD + c0];
    const uint4 p1 = *(const uint4*)&Pg[(size_t)n * HD + c0 + 8];
    const unsigned pw[8] = {p0.x, p0.y, p0.z, p0.w, p1.x, p1.y, p1.z, p1.w};
    unsigned outp[8];
#pragma unroll
    for (int cc = 0; cc < 8; ++cc) {
      const float vlo = fmaxf(funkey(keys[2 * cc])     + bflo(pw[cc]), 0.0f);
      const float vhi = fmaxf(funkey(keys[2 * cc + 1]) + bfhi(pw[cc]), 0.0f);
      outp[cc] = (unsigned)f2bf(vlo) | ((unsigned)f2bf(vhi) << 16);
    }
    __syncthreads();  // all key reads complete before aliased writes
#pragma unroll
    for (int cc = 0; cc < 8; ++cc)
      *(unsigned*)&agg[r * APAD + c0 + 2 * cc] = outp[cc];
  }
  __syncthreads();

  // ---- U-GEMM: wave w -> M-tile (w&1), cols [64*(w>>1), +64) ----
  const int mt = w & 1, nh = w >> 1;
  const int m = mt * 16 + (l & 15), q = l >> 4;
  bf16x8 afz[4], afa[4];
#pragma unroll
  for (int ks = 0; ks < 4; ++ks) {
    afz[ks] = *(const bf16x8*)&zsh[m * APAD + ks * 32 + q * 8];
    afa[ks] = *(const bf16x8*)&agg[m * APAD + ks * 32 + q * 8];
  }
  f32x4 acc4[4] = {{0, 0, 0, 0}, {0, 0, 0, 0}, {0, 0, 0, 0}, {0, 0, 0, 0}};
#pragma unroll
  for (int tt = 0; tt < 4; ++tt) {
    const int tn = nh * 4 + tt;
#pragma unroll
    for (int ks = 0; ks < 8; ++ks) {
      const bf16x8 bf = *(const bf16x8*)&Uf[((size_t)(tn * 8 + ks) * 64 + l) * 8];
      const bf16x8 a = (ks < 4) ? afz[ks] : afa[ks - 4];
      acc4[tt] = __builtin_amdgcn_mfma_f32_16x16x32_bf16(a, bf, acc4[tt], 0, 0, 0);
    }
  }
  // hsh writes only touch [8704,17408) — no overlap with agg [0,8704), safe
#pragma unroll
  for (int tt = 0; tt < 4; ++tt) {
    const int col = (nh * 4 + tt) * 16 + (l & 15);
    const float ub = U_b[col];
    float s4 = 0.0f;
#pragma unroll
    for (int r = 0; r < 4; ++r) {
      const int rowl = mt * 16 + q * 4 + r;
      const int n = n0 + rowl;
      float hv = fmaxf(acc4[tt][r] + ub, 0.0f);
      if (n < N) h_out[(size_t)n * HD + col] = hv; else hv = 0.0f;
      hsh[rowl * APAD + col] = f2bf(hv);
      s4 += hv;
    }
    atomicAdd(&hcol[col], s4);
  }
  __syncthreads();

  if (t < HD) atomicAdd(&hsum[t], hcol[t]);

  // ---- decoder: thread t -> node t>>3, cols (t&7)*16 .. +15 ----
  {
    const int r2 = t >> 3, s = t & 7;
    float part = 0.0f;
#pragma unroll
    for (int c = 0; c < 8; ++c) {
      const int kk = s * 16 + 2 * c;
      const unsigned zu = *(const unsigned*)&zsh[r2 * APAD + kk];
      const unsigned hu = *(const unsigned*)&hsh[r2 * APAD + kk];
      part += bflo(zu) * dec_w[kk] + bfhi(zu) * dec_w[kk + 1];
      part += bflo(hu) * dec_w[HD + kk] + bfhi(hu) * dec_w[HD + kk + 1];
    }
    pr[r2][s] = part;
  }
  __syncthreads();
  if (t < 32 && n0 + t < N) {
    float d = dec_b[0];
#pragma unroll
    for (int s = 0; s < 8; ++s) d += pr[t][s];
    y_out[n0 + t] = 1.0f / (1.0f + expf(-d));
  }
}

// ---------------------------------------------------------------------------
// K5: terminator. ter = (hsum/N) . (ter_w[:H] + ter_w[H:]) + ter_b
// ---------------------------------------------------------------------------
__global__ __launch_bounds__(128) void k_ter(
    const float* __restrict__ hsum, const float* __restrict__ ter_w,
    const float* __restrict__ ter_b, float* __restrict__ out, float invN) {
  __shared__ float r2[2];
  const int t = threadIdx.x;
  float v = (hsum[t] * invN) * (ter_w[t] + ter_w[HD + t]);
#pragma unroll
  for (int o = 32; o > 0; o >>= 1) v += __shfl_down(v, o);
  if ((t & 63) == 0) r2[t >> 6] = v;
  __syncthreads();
  if (t == 0) out[0] = r2[0] + r2[1] + ter_b[0];
}

// ---------------------------------------------------------------------------
extern "C" void kernel_launch(void* const* d_in, const int* in_sizes, int n_in,
                              void* d_out, int out_size, void* d_ws, size_t ws_size,
                              hipStream_t stream) {
  const float* x        = (const float*)d_in[0];
  const float* pre_h    = (const float*)d_in[1];
  const float* edge_attr= (const float*)d_in[2];
  const float* enc_w    = (const float*)d_in[3];
  const float* enc_b    = (const float*)d_in[4];
  const float* M_w      = (const float*)d_in[5];
  const float* M_b      = (const float*)d_in[6];
  const float* U_w      = (const float*)d_in[7];
  const float* U_b      = (const float*)d_in[8];
  const float* dec_w    = (const float*)d_in[9];
  const float* dec_b    = (const float*)d_in[10];
  const float* ter_w    = (const float*)d_in[11];
  const float* ter_b    = (const float*)d_in[12];
  const int*   edge_idx = (const int*)d_in[13];

  const int N = in_sizes[0];      // 50000
  const int E = in_sizes[2];      // 600000
  const size_t NH = (size_t)N * HD;
  const int nb = (N + 31) / 32;   // 1563 buckets

  float* out = (float*)d_out;
  float* h_out = out;             // [0, N*H)
  float* y_out = out + NH;        // [N*H, N*H+N)
  float* ter_out = out + NH + N;

  // ws layout: zg | Pg | Qg | epack(E int2) | encf | Pf | Qf | Uf
  //            | cnt(nb) | hsum(128) | bstart(nb+1) | cursor(nb)
  unsigned short* zg = (unsigned short*)d_ws;
  unsigned short* Pg = zg + NH;
  unsigned short* Qg = Pg + NH;
  int2* epack = (int2*)(Qg + NH);
  unsigned short* encf = (unsigned short*)(epack + E);
  unsigned short* Pf   = encf + 8 * 4 * 64 * 8;
  unsigned short* Qf   = Pf + 8 * 4 * 64 * 8;
  unsigned short* Uf   = Qf + 8 * 4 * 64 * 8;
  int*   cnt    = (int*)(Uf + 8 * 8 * 64 * 8);
  float* hsum   = (float*)(cnt + nb);
  int*   bstart = (int*)(hsum + HD);
  int*   cursor = bstart + nb + 1;

  // zero cnt + hsum in one shot
  hipMemsetAsync(cnt, 0, (nb + HD) * sizeof(int), stream);

  const int eb = (E + 255) / 256;  // 2344

  k_frag_hist<<<40 + eb, 256, 0, stream>>>(enc_w, M_w, U_w, encf, Pf, Qf, Uf,
                                           edge_idx, cnt, E);
  k_scan<<<1, 256, 0, stream>>>(cnt, bstart, cursor, nb);
  k_scatter<<<eb, 256, 0, stream>>>(edge_idx, edge_attr, cursor, epack, E);

  k_enc_pq<<<N / 16, 256, 0, stream>>>(x, pre_h, enc_w, enc_b, M_b,
                                       encf, Pf, Qf, zg, Pg, Qg);
  k_gather_update<<<nb, 256, 0, stream>>>(
      zg, Pg, Qg, M_w + 256 * HD, bstart, epack, Uf,
      U_b, dec_w, dec_b, h_out, y_out, hsum, N);
  k_ter<<<1, 128, 0, stream>>>(hsum, ter_w, ter_b, ter_out, 1.0f / (float)N);
}